// Round 1
// baseline (723.725 us; speedup 1.0000x reference)
//
#include <hip/hip_runtime.h>
#include <math.h>

typedef _Float16 f16x8 __attribute__((ext_vector_type(8)));
typedef float    f32x4 __attribute__((ext_vector_type(4)));

#define SEQ   2048
#define DH    64
#define BM    64            // q-rows per block (4 waves x 16 rows)
#define BK    64            // k-chunk per iteration
#define PITCH 72            // halves per LDS row: 64 + 8 pad -> 144B row, bank rotate 4
#define LOG2E 1.44269504088896340736f

// One wave = 16 q-rows, full Dh=64 (4 n-tiles of 16), flash-style online softmax.
// A-frag (16x16x32): A[m=lane&15][k=quad*8+j]  (verified layout, m120)
// B-frag:            B[k=quad*8+j][n=lane&15]  = x2[n][k]  (read from LDS fp16)
// C/D:               n=lane&15, m=quad*4+reg   (verified layout, m89/m91)
//
// x2 chunk [64 rows][64 cols] is staged ONCE per block per k-chunk into
// double-buffered LDS as fp16 (coalesced loads, shared by 4 waves) instead of
// each wave re-reading 16KB of scattered fp32 and re-converting per iteration.
extern "C" __global__ __launch_bounds__(256, 4)
void softmax_matmul_f16(const float* __restrict__ x1,
                        const float* __restrict__ x2,
                        float* __restrict__ out)
{
    __shared__ _Float16 ldsb[2][BM * PITCH];    // 2 x 9216 B = 18.4 KB

    const int tid  = threadIdx.x;
    const int wave = tid >> 6;
    const int lane = tid & 63;
    const int r    = lane & 15;     // q-row within wave tile / n within n-tile
    const int quad = lane >> 4;     // 0..3 -> k offset quad*8

    const int bh   = blockIdx.x >> 5;      // SEQ/BM = 32 q-blocks per bh
    const int qblk = blockIdx.x & 31;
    const int row0 = qblk * BM + wave * 16;

    const float* x1row = x1 + ((size_t)bh * SEQ + (size_t)(row0 + r)) * SEQ;
    const float* x2bh  = x2 + (size_t)bh * DH * SEQ;        // [64][2048]
    float*       obase = out + ((size_t)bh * SEQ + (size_t)row0) * DH;

    // block-wide staging role: thread -> (row sr, 16-float col group sc)
    const int sr = tid >> 2;            // 0..63
    const int sc = (tid & 3) * 16;      // 0,16,32,48
    const float* x2st = x2bh + (size_t)sr * SEQ + sc;
    _Float16* const ldsw0 = &ldsb[0][sr * PITCH + sc];
    _Float16* const ldsw1 = &ldsb[1][sr * PITCH + sc];

    f32x4 acc[4];
#pragma unroll
    for (int t = 0; t < 4; ++t) acc[t] = (f32x4){0.f, 0.f, 0.f, 0.f};

    float m = -INFINITY;
    float l = 0.0f;

    // ---- prologue: stage x2 chunk 0 into buf0 (coalesced: 64B contiguous/thread)
    {
        float4 s0 = *(const float4*)(x2st + 0);
        float4 s1 = *(const float4*)(x2st + 4);
        float4 s2 = *(const float4*)(x2st + 8);
        float4 s3 = *(const float4*)(x2st + 12);
        f16x8 h0, h1;
        h0[0] = (_Float16)s0.x; h0[1] = (_Float16)s0.y; h0[2] = (_Float16)s0.z; h0[3] = (_Float16)s0.w;
        h0[4] = (_Float16)s1.x; h0[5] = (_Float16)s1.y; h0[6] = (_Float16)s1.z; h0[7] = (_Float16)s1.w;
        h1[0] = (_Float16)s2.x; h1[1] = (_Float16)s2.y; h1[2] = (_Float16)s2.z; h1[3] = (_Float16)s2.w;
        h1[4] = (_Float16)s3.x; h1[5] = (_Float16)s3.y; h1[6] = (_Float16)s3.z; h1[7] = (_Float16)s3.w;
        *(f16x8*)(ldsw0 + 0) = h0;
        *(f16x8*)(ldsw0 + 8) = h1;
    }

    // ---- register prefetch of first x1 chunk (fragment pattern)
    const float* pf = x1row + quad * 8;
    float4 n0 = *(const float4*)(pf + 0);
    float4 n1 = *(const float4*)(pf + 4);
    float4 n2 = *(const float4*)(pf + 32);
    float4 n3 = *(const float4*)(pf + 36);

    __syncthreads();

    auto step = [&](int k0, const _Float16* __restrict__ rbase,
                    _Float16* __restrict__ wptr) {
        float xv[16];
        xv[0]  = n0.x; xv[1]  = n0.y; xv[2]  = n0.z; xv[3]  = n0.w;
        xv[4]  = n1.x; xv[5]  = n1.y; xv[6]  = n1.z; xv[7]  = n1.w;
        xv[8]  = n2.x; xv[9]  = n2.y; xv[10] = n2.z; xv[11] = n2.w;
        xv[12] = n3.x; xv[13] = n3.y; xv[14] = n3.z; xv[15] = n3.w;

        const int k1 = k0 + BK;
        const bool more = (k1 < SEQ);        // uniform branch
        float4 s0, s1, s2, s3;
        if (more) {
            // issue next-chunk loads EARLY: x1 frags + x2 stage (T14 issue-early)
            const float* pn = x1row + k1 + quad * 8;
            n0 = *(const float4*)(pn + 0);
            n1 = *(const float4*)(pn + 4);
            n2 = *(const float4*)(pn + 32);
            n3 = *(const float4*)(pn + 36);
            const float* ps = x2st + k1;
            s0 = *(const float4*)(ps + 0);
            s1 = *(const float4*)(ps + 4);
            s2 = *(const float4*)(ps + 8);
            s3 = *(const float4*)(ps + 12);
        }

        // ---- online softmax stats (rows live in lanes {r, r+16, r+32, r+48})
        // tree max (depth 4)
        float a0 = fmaxf(xv[0], xv[1]),  a1 = fmaxf(xv[2], xv[3]);
        float a2 = fmaxf(xv[4], xv[5]),  a3 = fmaxf(xv[6], xv[7]);
        float a4 = fmaxf(xv[8], xv[9]),  a5 = fmaxf(xv[10], xv[11]);
        float a6 = fmaxf(xv[12], xv[13]), a7 = fmaxf(xv[14], xv[15]);
        float b0 = fmaxf(a0, a1), b1 = fmaxf(a2, a3);
        float b2 = fmaxf(a4, a5), b3 = fmaxf(a6, a7);
        float cmax = fmaxf(fmaxf(b0, b1), fmaxf(b2, b3));
        cmax = fmaxf(cmax, __shfl_xor(cmax, 16));
        cmax = fmaxf(cmax, __shfl_xor(cmax, 32));

        const float mnew  = fmaxf(m, cmax);
        const float alpha = __builtin_amdgcn_exp2f((m - mnew) * LOG2E);
        const float sh    = mnew * LOG2E;

        float p[16];
#pragma unroll
        for (int j = 0; j < 16; ++j)
            p[j] = __builtin_amdgcn_exp2f(__builtin_fmaf(xv[j], LOG2E, -sh));

        // tree sum (depth 4)
        float c0 = p[0] + p[1],   c1 = p[2] + p[3];
        float c2 = p[4] + p[5],   c3 = p[6] + p[7];
        float c4 = p[8] + p[9],   c5 = p[10] + p[11];
        float c6 = p[12] + p[13], c7 = p[14] + p[15];
        float d0 = c0 + c1, d1 = c2 + c3, d2 = c4 + c5, d3 = c6 + c7;
        float rsum = (d0 + d1) + (d2 + d3);
        rsum += __shfl_xor(rsum, 16);
        rsum += __shfl_xor(rsum, 32);
        l = l * alpha + rsum;
        m = mnew;

        // ---- rescale accumulators: alpha for C-row quad*4+g lives in lane (quad*4+g)
        float ar[4];
#pragma unroll
        for (int g = 0; g < 4; ++g) ar[g] = __shfl(alpha, quad * 4 + g);
#pragma unroll
        for (int t = 0; t < 4; ++t)
#pragma unroll
            for (int g = 0; g < 4; ++g) acc[t][g] *= ar[g];

        // ---- A fragments (fp16, RNE)
        f16x8 ah0, ah1;
#pragma unroll
        for (int j = 0; j < 8; ++j) {
            ah0[j] = (_Float16)p[j];
            ah1[j] = (_Float16)p[8 + j];
        }

        // ---- B fragments from LDS fp16: one ds_read_b128 each, 2-way banks (free)
#pragma unroll
        for (int t = 0; t < 4; ++t) {
            const _Float16* bp = rbase + (t * 16 + r) * PITCH + quad * 8;
            f16x8 bf0 = *(const f16x8*)(bp);
            f16x8 bf1 = *(const f16x8*)(bp + 32);
            acc[t] = __builtin_amdgcn_mfma_f32_16x16x32_f16(ah0, bf0, acc[t], 0, 0, 0);
            acc[t] = __builtin_amdgcn_mfma_f32_16x16x32_f16(ah1, bf1, acc[t], 0, 0, 0);
        }

        // ---- write next x2 chunk to the other buffer (T14 write-late), then barrier
        if (more) {
            f16x8 h0, h1;
            h0[0] = (_Float16)s0.x; h0[1] = (_Float16)s0.y; h0[2] = (_Float16)s0.z; h0[3] = (_Float16)s0.w;
            h0[4] = (_Float16)s1.x; h0[5] = (_Float16)s1.y; h0[6] = (_Float16)s1.z; h0[7] = (_Float16)s1.w;
            h1[0] = (_Float16)s2.x; h1[1] = (_Float16)s2.y; h1[2] = (_Float16)s2.z; h1[3] = (_Float16)s2.w;
            h1[4] = (_Float16)s3.x; h1[5] = (_Float16)s3.y; h1[6] = (_Float16)s3.z; h1[7] = (_Float16)s3.w;
            *(f16x8*)(wptr + 0) = h0;
            *(f16x8*)(wptr + 8) = h1;
        }
        __syncthreads();
    };

    // 2x-unrolled so buffer selection is compile-time (no runtime-indexed buffers)
#pragma unroll 1
    for (int k0 = 0; k0 < SEQ; k0 += 2 * BK) {
        step(k0,      &ldsb[0][0], ldsw1);
        step(k0 + BK, &ldsb[1][0], ldsw0);
    }

    // ---- epilogue: divide by l (per-row), store C layout rows quad*4+g, col t*16+r
    const float rl = 1.0f / l;
    float rlr[4];
#pragma unroll
    for (int g = 0; g < 4; ++g) rlr[g] = __shfl(rl, quad * 4 + g);
#pragma unroll
    for (int t = 0; t < 4; ++t)
#pragma unroll
        for (int g = 0; g < 4; ++g)
            obase[(size_t)(quad * 4 + g) * DH + t * 16 + r] = acc[t][g] * rlr[g];
}

extern "C" void kernel_launch(void* const* d_in, const int* in_sizes, int n_in,
                              void* d_out, int out_size, void* d_ws, size_t ws_size,
                              hipStream_t stream)
{
    const float* x1 = (const float*)d_in[0];
    const float* x2 = (const float*)d_in[1];
    float* out = (float*)d_out;

    const int bhCount = in_sizes[1] / (DH * SEQ);   // B*H = 32
    dim3 grid(bhCount * (SEQ / BM));                // 1024 blocks
    dim3 block(256);
    hipLaunchKernelGGL(softmax_matmul_f16, grid, block, 0, stream, x1, x2, out);
}